// Round 4
// baseline (1917.665 us; speedup 1.0000x reference)
//
#include <hip/hip_runtime.h>
#include <hip/hip_bf16.h>
#include <cstdint>
#include <cstddef>

#define B_ 64
#define T_ 2048
#define D_ 256
#define H_ 256

// ---------------------------------------------------------------------------
// Kernel 1: projection GEMM  xp[b,t,:] = x[b,t,:] @ Wxh + b  (fp32 — the
// recurrence is chaotic: fp32 reorder noise alone gives absmax ~4e-3, i.e.
// amplification ~1e4. Any bf16/MFMA path would blow the 2e-2 threshold.)
// Written IN PLACE into d_out; recurrence overwrites each row after use.
// ---------------------------------------------------------------------------
#define PM 128
#define PN 128
#define PK 32

__global__ __launch_bounds__(256) void proj_kernel(const float* __restrict__ x,
                                                   const float* __restrict__ Wxh,
                                                   const float* __restrict__ bias,
                                                   float* __restrict__ xp) {
    __shared__ float As[PK][PM + 4];
    __shared__ float Bs[PK][PN + 4];
    const int tid = threadIdx.x;
    const int M0 = blockIdx.x * PM;
    const int N0 = blockIdx.y * PN;
    const int tr = tid >> 4;
    const int tc = tid & 15;

    float acc[8][8];
#pragma unroll
    for (int i = 0; i < 8; ++i)
#pragma unroll
        for (int j = 0; j < 8; ++j) acc[i][j] = 0.f;

    const int fA = tid & 7;
    const int rA = tid >> 3;
    const int kB = tid >> 3;
    const int fB = tid & 7;

    for (int kt = 0; kt < D_; kt += PK) {
#pragma unroll
        for (int i = 0; i < 4; ++i) {
            const int r = rA + i * 32;
            const float4 v = *(const float4*)&x[(size_t)(M0 + r) * D_ + kt + fA * 4];
            As[fA * 4 + 0][r] = v.x;
            As[fA * 4 + 1][r] = v.y;
            As[fA * 4 + 2][r] = v.z;
            As[fA * 4 + 3][r] = v.w;
        }
#pragma unroll
        for (int i = 0; i < 4; ++i) {
            const int c4 = fB + i * 8;
            const float4 v = *(const float4*)&Wxh[(size_t)(kt + kB) * H_ + N0 + c4 * 4];
            *(float4*)&Bs[kB][c4 * 4] = v;
        }
        __syncthreads();
#pragma unroll
        for (int k = 0; k < PK; ++k) {
            float a[8], bv[8];
            *(float4*)&a[0] = *(const float4*)&As[k][tr * 8];
            *(float4*)&a[4] = *(const float4*)&As[k][tr * 8 + 4];
            *(float4*)&bv[0] = *(const float4*)&Bs[k][tc * 8];
            *(float4*)&bv[4] = *(const float4*)&Bs[k][tc * 8 + 4];
#pragma unroll
            for (int i = 0; i < 8; ++i)
#pragma unroll
                for (int j = 0; j < 8; ++j)
                    acc[i][j] = fmaf(a[i], bv[j], acc[i][j]);
        }
        __syncthreads();
    }

    float bb[8];
    *(float4*)&bb[0] = *(const float4*)&bias[N0 + tc * 8];
    *(float4*)&bb[4] = *(const float4*)&bias[N0 + tc * 8 + 4];
#pragma unroll
    for (int i = 0; i < 8; ++i) {
        const size_t row = (size_t)(M0 + tr * 8 + i);
        float o[8];
#pragma unroll
        for (int j = 0; j < 8; ++j) o[j] = acc[i][j] + bb[j];
        *(float4*)&xp[row * H_ + N0 + tc * 8] = *(float4*)&o[0];
        *(float4*)&xp[row * H_ + N0 + tc * 8 + 4] = *(float4*)&o[4];
    }
}

// ---------------------------------------------------------------------------
// Kernel 2: recurrence. 64 blocks (1/batch), 512 threads, 1 block/CU.
// __launch_bounds__(512,2): VGPR cap 256 -> 128-float weight patch stays
// register-resident (R1: VGPR_Count=84 => per-step weight re-reads through
// L1/L2 ~= 970us chip-wide — the dominant cost).
// Fold 16 k-partials -> 8 via __shfl_xor over the half-wave boundary.
// (NOTE: NOT permlane32_swap(ai,ai) — tied-operand self-swap allocates both
// operands to one register => v_permlane32_swap v5,v5 == plain half swap,
// folded = 2*partner-half. That was R2/R3's absmax=1.95 failure.)
// ---------------------------------------------------------------------------
__global__ __launch_bounds__(512, 2) void rnn_kernel(const float* __restrict__ Whh,
                                                     float* __restrict__ io) {
    __shared__ float h_lds[H_];
    __shared__ float part[8 * 260];  // 8 rows, 260-float stride (16B-aligned)

    const int tid = threadIdx.x;
    const int b = blockIdx.x;
    const int colg = tid & 31;
    const int p = tid >> 5;
    const int w = tid >> 6;     // wave id 0..7
    const int lane = tid & 63;
    const int j0 = colg * 8;
    const int k0 = p * 16;

    // 16x8 fp32 weight patch -> 128 VGPRs (coalesced float4 row reads).
    float wreg[16][8];
#pragma unroll
    for (int kk = 0; kk < 16; ++kk) {
        const float4 v0 = *(const float4*)&Whh[(size_t)(k0 + kk) * H_ + j0];
        const float4 v1 = *(const float4*)&Whh[(size_t)(k0 + kk) * H_ + j0 + 4];
        wreg[kk][0] = v0.x; wreg[kk][1] = v0.y; wreg[kk][2] = v0.z; wreg[kk][3] = v0.w;
        wreg[kk][4] = v1.x; wreg[kk][5] = v1.y; wreg[kk][6] = v1.z; wreg[kk][7] = v1.w;
    }

    float* row_base = io + (size_t)b * T_ * H_;
    float xp0 = 0.f, xp1 = 0.f;
    if (tid < H_) {
        h_lds[tid] = 0.f;
        xp0 = row_base[tid];
        xp1 = row_base[H_ + tid];
    }
    __syncthreads();

    for (int t = 0; t < T_; ++t) {
        // depth-2 prefetch of xp row t+2 (L2/L3-resident; hidden under compute)
        float xp2 = 0.f;
        if (tid < H_ && (t + 2) < T_) xp2 = row_base[(size_t)(t + 2) * H_ + tid];

        // ---- partial matvec: acc[c] = sum_{kk<16} h[k0+kk] * Whh[k0+kk][j0+c]
        float acc[8];
#pragma unroll
        for (int c = 0; c < 8; ++c) acc[c] = 0.f;
        const float4* h4 = (const float4*)h_lds;
#pragma unroll
        for (int i = 0; i < 4; ++i) {
            const float4 hv = h4[p * 4 + i];  // per-wave: 2 bcast addrs (cheap)
            const float hs[4] = {hv.x, hv.y, hv.z, hv.w};
#pragma unroll
            for (int q = 0; q < 4; ++q) {
                const int kk = i * 4 + q;
#pragma unroll
                for (int c = 0; c < 8; ++c)
                    acc[c] = fmaf(hs[q], wreg[kk][c], acc[c]);
            }
        }

        // ---- fold half-waves: p=2w (lanes 0-31) + p=2w+1 (lanes 32-63).
        // Uniform control flow; all 64 lanes execute the shuffle.
        float folded[8];
#pragma unroll
        for (int c = 0; c < 8; ++c)
            folded[c] = acc[c] + __shfl_xor(acc[c], 32, 64);

        // ---- lanes 0-31 write part row w, slot-interleaved:
        // f4#0 (cols j0..j0+3) at [w*260 + colg*4], f4#1 at +128 floats.
        if (lane < 32) {
            float* dst = &part[w * 260 + colg * 4];
            *(float4*)dst         = make_float4(folded[0], folded[1], folded[2], folded[3]);
            *(float4*)(dst + 128) = make_float4(folded[4], folded[5], folded[6], folded[7]);
        }
        __syncthreads();

        // ---- final reduce over 8 rows (2-way bank aliasing = free), tanh, h.
        if (tid < H_) {
            const int idx = ((tid & 4) << 5) + ((tid >> 3) << 2) + (tid & 3);
            float s = xp0;
#pragma unroll
            for (int ww = 0; ww < 8; ++ww) s += part[ww * 260 + idx];
            const float h = tanhf(s);
            h_lds[tid] = h;
            row_base[(size_t)t * H_ + tid] = h;
            xp0 = xp1;
            xp1 = xp2;
        }
        __syncthreads();
    }
}

// ---------------------------------------------------------------------------
extern "C" void kernel_launch(void* const* d_in, const int* in_sizes, int n_in,
                              void* d_out, int out_size, void* d_ws, size_t ws_size,
                              hipStream_t stream) {
    const float* x    = (const float*)d_in[0];
    const float* Wxh  = (const float*)d_in[1];
    const float* Whh  = (const float*)d_in[2];
    const float* bias = (const float*)d_in[3];
    float* out = (float*)d_out;

    dim3 pgrid((B_ * T_) / PM, H_ / PN);  // 1024 x 2
    proj_kernel<<<pgrid, dim3(256), 0, stream>>>(x, Wxh, bias, out);
    rnn_kernel<<<dim3(B_), dim3(512), 0, stream>>>(Whh, out);
}